// Round 1
// baseline (1077.745 us; speedup 1.0000x reference)
//
#include <hip/hip_runtime.h>
#include <stdint.h>

// Problem constants
#define BATCH 4
#define S_LEN 4096
#define D_DIM 1024
static constexpr float ATTN_SCALE = 0.03125f; // 1/sqrt(1024)

typedef __attribute__((ext_vector_type(8))) short short8_t;
typedef __attribute__((ext_vector_type(4))) float f32x4;

// ---------- bf16 helpers (manual RNE, bits in unsigned short) ----------
__device__ __forceinline__ unsigned short f2b(float f) {
    union { float f; uint32_t i; } x; x.f = f;
    uint32_t r = x.i + 0x7FFF + ((x.i >> 16) & 1);
    return (unsigned short)(r >> 16);
}
__device__ __forceinline__ float b2f(unsigned short u) {
    union { uint32_t i; float f; } x; x.i = ((uint32_t)u) << 16;
    return x.f;
}

// ---------- async global->LDS 16B ----------
__device__ __forceinline__ void gl_lds16(const unsigned short* g, unsigned short* l) {
    __builtin_amdgcn_global_load_lds(
        (const __attribute__((address_space(1))) uint32_t*)(const void*)g,
        (__attribute__((address_space(3))) uint32_t*)(void*)l,
        16, 0, 0);
}

// ---------- cast fp32 -> bf16, 8 elements/thread ----------
__global__ __launch_bounds__(256) void cast_f32_bf16(
    const float* __restrict__ in, unsigned short* __restrict__ out, int n) {
    int i = (blockIdx.x * 256 + threadIdx.x) * 8;
    if (i >= n) return;
    float4 a = *(const float4*)(in + i);
    float4 b = *(const float4*)(in + i + 4);
    short8_t o;
    o[0] = (short)f2b(a.x); o[1] = (short)f2b(a.y);
    o[2] = (short)f2b(a.z); o[3] = (short)f2b(a.w);
    o[4] = (short)f2b(b.x); o[5] = (short)f2b(b.y);
    o[6] = (short)f2b(b.z); o[7] = (short)f2b(b.w);
    *(short8_t*)(out + i) = o;
}

// ---------- C store dispatch ----------
__device__ __forceinline__ void storeC(float* p, float v) { *p = v; }
__device__ __forceinline__ void storeC(unsigned short* p, float v) { *p = f2b(v); }

// ---------- GEMM: C[M,N] = scale * (A[M,K] @ B[N,K]^T) + bias ----------
// A, B bf16 row-major, K-contiguous. 128x128 tile, 256 threads (4 waves),
// each wave does a 64x64 subtile as 4x4 grid of 16x16x32 bf16 MFMAs.
template <typename OutT>
__global__ __launch_bounds__(256) void gemm_bt(
    const unsigned short* __restrict__ A, const unsigned short* __restrict__ B,
    OutT* __restrict__ C, const float* __restrict__ bias,
    int M, int N, int K, float scale) {
    __shared__ __align__(16) unsigned short As[128 * 32];
    __shared__ __align__(16) unsigned short Bs[128 * 32];

    const int tid  = threadIdx.x;
    const int wave = tid >> 6;
    const int lane = tid & 63;
    const int m0 = blockIdx.y * 128;
    const int n0 = blockIdx.x * 128;
    const int wm = (wave >> 1) * 64;
    const int wn = (wave & 1) * 64;
    const int lm = lane & 15;
    const int quad = lane >> 4;

    f32x4 acc[4][4];
#pragma unroll
    for (int i = 0; i < 4; ++i)
#pragma unroll
        for (int j = 0; j < 4; ++j)
#pragma unroll
            for (int e = 0; e < 4; ++e) acc[i][j][e] = 0.f;

    // staging chunk mapping: chunk c (16B) -> row c>>2, k-offset (c&3)*8
    const int c0 = tid, c1 = tid + 256;
    const int r0 = c0 >> 2, kc0 = (c0 & 3) << 3;
    const int r1 = c1 >> 2, kc1 = (c1 & 3) << 3;
    const unsigned short* Ar0 = A + (size_t)(m0 + r0) * K + kc0;
    const unsigned short* Ar1 = A + (size_t)(m0 + r1) * K + kc1;
    const unsigned short* Br0 = B + (size_t)(n0 + r0) * K + kc0;
    const unsigned short* Br1 = B + (size_t)(n0 + r1) * K + kc1;

    for (int k0 = 0; k0 < K; k0 += 32) {
        gl_lds16(Ar0 + k0, &As[c0 * 8]);
        gl_lds16(Ar1 + k0, &As[c1 * 8]);
        gl_lds16(Br0 + k0, &Bs[c0 * 8]);
        gl_lds16(Br1 + k0, &Bs[c1 * 8]);
        __syncthreads();

        short8_t af[4], bf[4];
#pragma unroll
        for (int mi = 0; mi < 4; ++mi)
            af[mi] = *(const short8_t*)&As[(wm + mi * 16 + lm) * 32 + quad * 8];
#pragma unroll
        for (int ni = 0; ni < 4; ++ni)
            bf[ni] = *(const short8_t*)&Bs[(wn + ni * 16 + lm) * 32 + quad * 8];
#pragma unroll
        for (int mi = 0; mi < 4; ++mi)
#pragma unroll
            for (int ni = 0; ni < 4; ++ni)
                acc[mi][ni] = __builtin_amdgcn_mfma_f32_16x16x32_bf16(
                    af[mi], bf[ni], acc[mi][ni], 0, 0, 0);
        __syncthreads();
    }

    // epilogue: C/D layout col = lane&15, row = quad*4 + reg
#pragma unroll
    for (int ni = 0; ni < 4; ++ni) {
        const int col = n0 + wn + ni * 16 + lm;
        const float bv = bias ? bias[col] : 0.f;
#pragma unroll
        for (int mi = 0; mi < 4; ++mi) {
#pragma unroll
            for (int e = 0; e < 4; ++e) {
                const int row = m0 + wm + mi * 16 + quad * 4 + e;
                storeC(&C[(size_t)row * N + col], acc[mi][ni][e] * scale + bv);
            }
        }
    }
}

// ---------- row softmax over 4096-wide rows, bf16 in/out in place ----------
__global__ __launch_bounds__(256) void softmax_rows(unsigned short* __restrict__ P) {
    const int row = blockIdx.x;
    unsigned short* p = P + (size_t)row * S_LEN;
    const int t = threadIdx.x;

    // thread t handles contiguous elements [16t, 16t+16)
    short8_t r0 = ((const short8_t*)p)[2 * t];
    short8_t r1 = ((const short8_t*)p)[2 * t + 1];
    float v[16];
    float m = -1e30f;
#pragma unroll
    for (int i = 0; i < 8; ++i) { v[i] = b2f((unsigned short)r0[i]); m = fmaxf(m, v[i]); }
#pragma unroll
    for (int i = 0; i < 8; ++i) { v[8 + i] = b2f((unsigned short)r1[i]); m = fmaxf(m, v[8 + i]); }

#pragma unroll
    for (int off = 32; off >= 1; off >>= 1) m = fmaxf(m, __shfl_xor(m, off));
    __shared__ float redm[4];
    if ((t & 63) == 0) redm[t >> 6] = m;
    __syncthreads();
    m = fmaxf(fmaxf(redm[0], redm[1]), fmaxf(redm[2], redm[3]));

    float s = 0.f;
#pragma unroll
    for (int i = 0; i < 16; ++i) { v[i] = __expf(v[i] - m); s += v[i]; }
#pragma unroll
    for (int off = 32; off >= 1; off >>= 1) s += __shfl_xor(s, off);
    __shared__ float reds[4];
    if ((t & 63) == 0) reds[t >> 6] = s;
    __syncthreads();
    s = reds[0] + reds[1] + reds[2] + reds[3];
    const float inv = 1.f / s;

    short8_t w0, w1;
#pragma unroll
    for (int i = 0; i < 8; ++i) w0[i] = (short)f2b(v[i] * inv);
#pragma unroll
    for (int i = 0; i < 8; ++i) w1[i] = (short)f2b(v[8 + i] * inv);
    ((short8_t*)p)[2 * t] = w0;
    ((short8_t*)p)[2 * t + 1] = w1;
}

// ---------- transpose [S,D] -> [D,S] bf16, per batch (blockIdx.z) ----------
__global__ __launch_bounds__(256) void transpose_sd(
    const unsigned short* __restrict__ V, unsigned short* __restrict__ VT) {
    __shared__ unsigned short tile[32][33];
    const size_t bi = (size_t)blockIdx.z * S_LEN * D_DIM;
    const size_t bo = (size_t)blockIdx.z * D_DIM * S_LEN;
    const int d = blockIdx.x * 32 + threadIdx.x;
    const int s = blockIdx.y * 32 + threadIdx.y;
#pragma unroll
    for (int j = 0; j < 32; j += 8)
        tile[threadIdx.y + j][threadIdx.x] = V[bi + (size_t)(s + j) * D_DIM + d];
    __syncthreads();
    const int d2 = blockIdx.x * 32 + threadIdx.y;
    const int s2 = blockIdx.y * 32 + threadIdx.x;
#pragma unroll
    for (int j = 0; j < 32; j += 8)
        VT[bo + (size_t)(d2 + j) * S_LEN + s2] = tile[threadIdx.x][threadIdx.y + j];
}

extern "C" void kernel_launch(void* const* d_in, const int* in_sizes, int n_in,
                              void* d_out, int out_size, void* d_ws, size_t ws_size,
                              hipStream_t stream) {
    const float* x  = (const float*)d_in[0];
    const float* Wq = (const float*)d_in[1];
    const float* bq = (const float*)d_in[2];
    const float* Wk = (const float*)d_in[3];
    const float* bk = (const float*)d_in[4];
    const float* Wv = (const float*)d_in[5];
    const float* bv = (const float*)d_in[6];
    const float* Wo = (const float*)d_in[7];
    const float* bo = (const float*)d_in[8];
    float* out = (float*)d_out;

    char* ws = (char*)d_ws;
    const size_t MB = 1ull << 20;
    // layout (total 176 MB): P aliases xb (x_bf16 dead after projections)
    unsigned short* xb  = (unsigned short*)(ws + 0);        // 32 MB
    unsigned short* Pb  = (unsigned short*)(ws + 0);        // 32 MB (alias, used later)
    unsigned short* Wqb = (unsigned short*)(ws + 32 * MB);  // 2 MB
    unsigned short* Wkb = (unsigned short*)(ws + 34 * MB);
    unsigned short* Wvb = (unsigned short*)(ws + 36 * MB);
    unsigned short* Wob = (unsigned short*)(ws + 38 * MB);
    unsigned short* qb  = (unsigned short*)(ws + 40 * MB);  // 32 MB
    unsigned short* kb  = (unsigned short*)(ws + 72 * MB);  // 32 MB
    unsigned short* vb  = (unsigned short*)(ws + 104 * MB); // 32 MB
    unsigned short* vtb = (unsigned short*)(ws + 136 * MB); // 32 MB
    unsigned short* ctx = (unsigned short*)(ws + 168 * MB); // 8 MB (one batch)

    const int nX = BATCH * S_LEN * D_DIM; // 16777216
    const int nW = D_DIM * D_DIM;         // 1048576

    cast_f32_bf16<<<nX / 8 / 256, 256, 0, stream>>>(x, xb, nX);
    cast_f32_bf16<<<nW / 8 / 256, 256, 0, stream>>>(Wq, Wqb, nW);
    cast_f32_bf16<<<nW / 8 / 256, 256, 0, stream>>>(Wk, Wkb, nW);
    cast_f32_bf16<<<nW / 8 / 256, 256, 0, stream>>>(Wv, Wvb, nW);
    cast_f32_bf16<<<nW / 8 / 256, 256, 0, stream>>>(Wo, Wob, nW);

    // projections: [16384,1024] = x @ W^T + b, bf16 out
    dim3 gproj(D_DIM / 128, (BATCH * S_LEN) / 128); // (8,128)
    gemm_bt<unsigned short><<<gproj, 256, 0, stream>>>(xb, Wqb, qb, bq,
        BATCH * S_LEN, D_DIM, D_DIM, 1.f);
    gemm_bt<unsigned short><<<gproj, 256, 0, stream>>>(xb, Wkb, kb, bk,
        BATCH * S_LEN, D_DIM, D_DIM, 1.f);
    gemm_bt<unsigned short><<<gproj, 256, 0, stream>>>(xb, Wvb, vb, bv,
        BATCH * S_LEN, D_DIM, D_DIM, 1.f);

    // v -> v^T per batch (for context GEMM in A@B^T form)
    transpose_sd<<<dim3(D_DIM / 32, S_LEN / 32, BATCH), dim3(32, 8), 0, stream>>>(vb, vtb);

    for (int b = 0; b < BATCH; ++b) {
        const size_t sd = (size_t)b * S_LEN * D_DIM;
        const size_t ds = (size_t)b * D_DIM * S_LEN;
        // scores = scale * q @ k^T  -> Pb (bf16)
        gemm_bt<unsigned short><<<dim3(S_LEN / 128, S_LEN / 128), 256, 0, stream>>>(
            qb + sd, kb + sd, Pb, nullptr, S_LEN, S_LEN, D_DIM, ATTN_SCALE);
        // softmax rows in place
        softmax_rows<<<S_LEN, 256, 0, stream>>>(Pb);
        // context = P @ V = P @ (V^T)^T -> ctx (bf16)
        gemm_bt<unsigned short><<<dim3(D_DIM / 128, S_LEN / 128), 256, 0, stream>>>(
            Pb, vtb + ds, ctx, nullptr, S_LEN, D_DIM, S_LEN, 1.f);
        // out = ctx @ Wo^T + bo (fp32)
        gemm_bt<float><<<dim3(D_DIM / 128, S_LEN / 128), 256, 0, stream>>>(
            ctx, Wob, out + sd, bo, S_LEN, D_DIM, D_DIM, 1.f);
    }
}

// Round 2
// 820.704 us; speedup vs baseline: 1.3132x; 1.3132x over previous
//
#include <hip/hip_runtime.h>
#include <stdint.h>

#define BATCH 4
#define S_LEN 4096
#define D_DIM 1024
static constexpr float ATTN_SCALE = 0.03125f; // 1/sqrt(1024)

typedef __attribute__((ext_vector_type(8))) short short8_t;
typedef __attribute__((ext_vector_type(4))) float f32x4;

// ---------- bf16 helpers ----------
__device__ __forceinline__ unsigned short f2b(float f) {
    union { float f; uint32_t i; } x; x.f = f;
    uint32_t r = x.i + 0x7FFF + ((x.i >> 16) & 1);
    return (unsigned short)(r >> 16);
}
__device__ __forceinline__ float b2f(unsigned short u) {
    union { uint32_t i; float f; } x; x.i = ((uint32_t)u) << 16;
    return x.f;
}

// ---------- async global->LDS 16B ----------
__device__ __forceinline__ void gl_lds16(const unsigned short* g, unsigned short* l) {
    __builtin_amdgcn_global_load_lds(
        (const __attribute__((address_space(1))) uint32_t*)(const void*)g,
        (__attribute__((address_space(3))) uint32_t*)(void*)l,
        16, 0, 0);
}

// ---------- cast fp32 -> bf16, 8 elems/thread ----------
__global__ __launch_bounds__(256) void cast_f32_bf16(
    const float* __restrict__ in, unsigned short* __restrict__ out, int n) {
    int i = (blockIdx.x * 256 + threadIdx.x) * 8;
    if (i >= n) return;
    float4 a = *(const float4*)(in + i);
    float4 b = *(const float4*)(in + i + 4);
    short8_t o;
    o[0] = (short)f2b(a.x); o[1] = (short)f2b(a.y);
    o[2] = (short)f2b(a.z); o[3] = (short)f2b(a.w);
    o[4] = (short)f2b(b.x); o[5] = (short)f2b(b.y);
    o[6] = (short)f2b(b.z); o[7] = (short)f2b(b.w);
    *(short8_t*)(out + i) = o;
}

// ---------- pack 3 fp32 bias vectors into one [3072] ----------
__global__ __launch_bounds__(256) void pack_bias(
    const float* __restrict__ bq, const float* __restrict__ bk,
    const float* __restrict__ bv, float* __restrict__ o) {
    int i = blockIdx.x * 256 + threadIdx.x; // 3072 total
    float v = (i < 1024) ? bq[i] : (i < 2048 ? bk[i - 1024] : bv[i - 2048]);
    o[i] = v;
}

__device__ __forceinline__ void storeC(float* p, float v) { *p = v; }
__device__ __forceinline__ void storeC(unsigned short* p, float v) { *p = f2b(v); }

// ---------- GEMM: C[M,N] = scale*(A @ B^T) + bias, batched via blockIdx.z ----------
// A,B bf16 row-major K-contiguous with leading dims; 128x128 tile, 4 waves,
// 64x64/wave as 4x4 of 16x16x32 bf16 MFMA. m97 structure.
template <typename OutT>
__global__ __launch_bounds__(256) void gemm_bt(
    const unsigned short* __restrict__ A, const unsigned short* __restrict__ B,
    OutT* __restrict__ C, const float* __restrict__ bias,
    int M, int N, int K, int lda, int ldb, int ldc,
    size_t sA, size_t sB, size_t sC, float scale) {
    __shared__ __align__(16) unsigned short As[128 * 32];
    __shared__ __align__(16) unsigned short Bs[128 * 32];

    A += (size_t)blockIdx.z * sA;
    B += (size_t)blockIdx.z * sB;
    C += (size_t)blockIdx.z * sC;

    const int tid  = threadIdx.x;
    const int wave = tid >> 6;
    const int lane = tid & 63;
    const int m0 = blockIdx.y * 128;
    const int n0 = blockIdx.x * 128;
    const int wm = (wave >> 1) * 64;
    const int wn = (wave & 1) * 64;
    const int lm = lane & 15;
    const int quad = lane >> 4;

    f32x4 acc[4][4];
#pragma unroll
    for (int i = 0; i < 4; ++i)
#pragma unroll
        for (int j = 0; j < 4; ++j)
#pragma unroll
            for (int e = 0; e < 4; ++e) acc[i][j][e] = 0.f;

    const int c0 = tid, c1 = tid + 256;
    const int r0 = c0 >> 2, kc0 = (c0 & 3) << 3;
    const int r1 = c1 >> 2, kc1 = (c1 & 3) << 3;
    const unsigned short* Ar0 = A + (size_t)(m0 + r0) * lda + kc0;
    const unsigned short* Ar1 = A + (size_t)(m0 + r1) * lda + kc1;
    const unsigned short* Br0 = B + (size_t)(n0 + r0) * ldb + kc0;
    const unsigned short* Br1 = B + (size_t)(n0 + r1) * ldb + kc1;

    for (int k0 = 0; k0 < K; k0 += 32) {
        gl_lds16(Ar0 + k0, &As[c0 * 8]);
        gl_lds16(Ar1 + k0, &As[c1 * 8]);
        gl_lds16(Br0 + k0, &Bs[c0 * 8]);
        gl_lds16(Br1 + k0, &Bs[c1 * 8]);
        __syncthreads();

        short8_t af[4], bf[4];
#pragma unroll
        for (int mi = 0; mi < 4; ++mi)
            af[mi] = *(const short8_t*)&As[(wm + mi * 16 + lm) * 32 + quad * 8];
#pragma unroll
        for (int ni = 0; ni < 4; ++ni)
            bf[ni] = *(const short8_t*)&Bs[(wn + ni * 16 + lm) * 32 + quad * 8];
#pragma unroll
        for (int mi = 0; mi < 4; ++mi)
#pragma unroll
            for (int ni = 0; ni < 4; ++ni)
                acc[mi][ni] = __builtin_amdgcn_mfma_f32_16x16x32_bf16(
                    af[mi], bf[ni], acc[mi][ni], 0, 0, 0);
        __syncthreads();
    }

    // epilogue: C/D layout col = lane&15, row = quad*4 + reg
#pragma unroll
    for (int ni = 0; ni < 4; ++ni) {
        const int col = n0 + wn + ni * 16 + lm;
        const float bv = bias ? bias[col] : 0.f;
#pragma unroll
        for (int mi = 0; mi < 4; ++mi) {
#pragma unroll
            for (int e = 0; e < 4; ++e) {
                const int row = m0 + wm + mi * 16 + quad * 4 + e;
                storeC(&C[(size_t)row * ldc + col], acc[mi][ni][e] * scale + bv);
            }
        }
    }
}

// ---------- row softmax over 4096-wide bf16 rows, in place ----------
__global__ __launch_bounds__(256) void softmax_rows(unsigned short* __restrict__ P) {
    const int row = blockIdx.x;
    unsigned short* p = P + (size_t)row * S_LEN;
    const int t = threadIdx.x;

    short8_t r0 = ((const short8_t*)p)[2 * t];
    short8_t r1 = ((const short8_t*)p)[2 * t + 1];
    float v[16];
    float m = -1e30f;
#pragma unroll
    for (int i = 0; i < 8; ++i) { v[i] = b2f((unsigned short)r0[i]); m = fmaxf(m, v[i]); }
#pragma unroll
    for (int i = 0; i < 8; ++i) { v[8 + i] = b2f((unsigned short)r1[i]); m = fmaxf(m, v[8 + i]); }

#pragma unroll
    for (int off = 32; off >= 1; off >>= 1) m = fmaxf(m, __shfl_xor(m, off));
    __shared__ float redm[4];
    if ((t & 63) == 0) redm[t >> 6] = m;
    __syncthreads();
    m = fmaxf(fmaxf(redm[0], redm[1]), fmaxf(redm[2], redm[3]));

    float s = 0.f;
#pragma unroll
    for (int i = 0; i < 16; ++i) { v[i] = __expf(v[i] - m); s += v[i]; }
#pragma unroll
    for (int off = 32; off >= 1; off >>= 1) s += __shfl_xor(s, off);
    __shared__ float reds[4];
    if ((t & 63) == 0) reds[t >> 6] = s;
    __syncthreads();
    s = reds[0] + reds[1] + reds[2] + reds[3];
    const float inv = 1.f / s;

    short8_t w0, w1;
#pragma unroll
    for (int i = 0; i < 8; ++i) w0[i] = (short)f2b(v[i] * inv);
#pragma unroll
    for (int i = 0; i < 8; ++i) w1[i] = (short)f2b(v[8 + i] * inv);
    ((short8_t*)p)[2 * t] = w0;
    ((short8_t*)p)[2 * t + 1] = w1;
}

// ---------- transpose [S,D]->[D,S] bf16, batched via blockIdx.z ----------
__global__ __launch_bounds__(256) void transpose_sd(
    const unsigned short* __restrict__ src, int srcLd, size_t sSrc,
    unsigned short* __restrict__ dst, size_t sDst) {
    __shared__ unsigned short tile[32][33];
    src += (size_t)blockIdx.z * sSrc;
    dst += (size_t)blockIdx.z * sDst;
    const int d = blockIdx.x * 32 + threadIdx.x;
    const int s = blockIdx.y * 32 + threadIdx.y;
#pragma unroll
    for (int j = 0; j < 32; j += 8)
        tile[threadIdx.y + j][threadIdx.x] = src[(size_t)(s + j) * srcLd + d];
    __syncthreads();
    const int d2 = blockIdx.x * 32 + threadIdx.y;
    const int s2 = blockIdx.y * 32 + threadIdx.x;
#pragma unroll
    for (int j = 0; j < 32; j += 8)
        dst[(size_t)(d2 + j) * S_LEN + s2] = tile[threadIdx.x][threadIdx.y + j];
}

extern "C" void kernel_launch(void* const* d_in, const int* in_sizes, int n_in,
                              void* d_out, int out_size, void* d_ws, size_t ws_size,
                              hipStream_t stream) {
    const float* x  = (const float*)d_in[0];
    const float* Wq = (const float*)d_in[1];
    const float* bq = (const float*)d_in[2];
    const float* Wk = (const float*)d_in[3];
    const float* bk = (const float*)d_in[4];
    const float* Wv = (const float*)d_in[5];
    const float* bv = (const float*)d_in[6];
    const float* Wo = (const float*)d_in[7];
    const float* bo = (const float*)d_in[8];
    float* out = (float*)d_out;

    char* ws = (char*)d_ws;
    const size_t MB = 1ull << 20;
    const int nX = BATCH * S_LEN * D_DIM; // 16777216
    const int nW = D_DIM * D_DIM;         // 1048576
    const int SR = BATCH * S_LEN;         // 16384 total rows

    // group size for the attention phase: P needs nb*32MB beyond the 169MB base
    int nb = 0;
    if (ws_size >= 169 * MB + 32 * MB)
        nb = (int)((ws_size - 169 * MB) / (32 * MB));
    if (nb > BATCH) nb = BATCH;

    if (nb >= 1) {
        // -------- main path: fused QKV + batched attention --------
        // layout: qkvb[0,96) Wqkvb[96,102) Wob[102,104) bqkv[104,105)
        //         xb[105,137) (dead after QKV gemm; vtb aliases it)
        //         ctx[137,169)  P[169,169+nb*32)
        unsigned short* qkvb  = (unsigned short*)(ws + 0);
        unsigned short* Wqkvb = (unsigned short*)(ws + 96 * MB);
        unsigned short* Wob   = (unsigned short*)(ws + 102 * MB);
        float*          bqkv  = (float*)(ws + 104 * MB);
        unsigned short* xb    = (unsigned short*)(ws + 105 * MB);
        unsigned short* vtb   = (unsigned short*)(ws + 105 * MB); // alias xb
        unsigned short* ctx   = (unsigned short*)(ws + 137 * MB);
        unsigned short* Pb    = (unsigned short*)(ws + 169 * MB);

        cast_f32_bf16<<<nX / 2048, 256, 0, stream>>>(x, xb, nX);
        cast_f32_bf16<<<nW / 2048, 256, 0, stream>>>(Wq, Wqkvb, nW);
        cast_f32_bf16<<<nW / 2048, 256, 0, stream>>>(Wk, Wqkvb + nW, nW);
        cast_f32_bf16<<<nW / 2048, 256, 0, stream>>>(Wv, Wqkvb + 2 * nW, nW);
        cast_f32_bf16<<<nW / 2048, 256, 0, stream>>>(Wo, Wob, nW);
        pack_bias<<<12, 256, 0, stream>>>(bq, bk, bv, bqkv);

        // QKV: [16384,3072] = x @ Wqkv^T + bqkv  (3072 blocks)
        gemm_bt<unsigned short><<<dim3(3072 / 128, SR / 128, 1), 256, 0, stream>>>(
            xb, Wqkvb, qkvb, bqkv, SR, 3072, D_DIM,
            D_DIM, D_DIM, 3072, 0, 0, 0, 1.f);

        // v columns of qkvb -> vtb [B][D][S]
        transpose_sd<<<dim3(D_DIM / 32, S_LEN / 32, BATCH), dim3(32, 8), 0, stream>>>(
            qkvb + 2048, 3072, (size_t)S_LEN * 3072, vtb, (size_t)D_DIM * S_LEN);

        const unsigned short* qp = qkvb;
        const unsigned short* kp = qkvb + 1024;
        for (int b0 = 0; b0 < BATCH; b0 += nb) {
            int g = (BATCH - b0 < nb) ? (BATCH - b0) : nb;
            const size_t qoff = (size_t)b0 * S_LEN * 3072;
            // scores: P[g][S][S] = scale * q @ k^T   (g*1024 blocks)
            gemm_bt<unsigned short><<<dim3(S_LEN / 128, S_LEN / 128, g), 256, 0, stream>>>(
                qp + qoff, kp + qoff, Pb, nullptr, S_LEN, S_LEN, D_DIM,
                3072, 3072, S_LEN,
                (size_t)S_LEN * 3072, (size_t)S_LEN * 3072, (size_t)S_LEN * S_LEN,
                ATTN_SCALE);
            softmax_rows<<<g * S_LEN, 256, 0, stream>>>(Pb);
            // context: ctx[g][S][D] = P @ (V^T)^T   (g*256 blocks, K=4096)
            gemm_bt<unsigned short><<<dim3(D_DIM / 128, S_LEN / 128, g), 256, 0, stream>>>(
                Pb, vtb + (size_t)b0 * D_DIM * S_LEN,
                ctx + (size_t)b0 * S_LEN * D_DIM, nullptr,
                S_LEN, D_DIM, S_LEN,
                S_LEN, S_LEN, D_DIM,
                (size_t)S_LEN * S_LEN, (size_t)D_DIM * S_LEN, (size_t)S_LEN * D_DIM,
                1.f);
        }

        // out = ctx @ Wo^T + bo over all 16384 rows (1024 blocks)
        gemm_bt<float><<<dim3(D_DIM / 128, SR / 128, 1), 256, 0, stream>>>(
            ctx, Wob, out, bo, SR, D_DIM, D_DIM,
            D_DIM, D_DIM, D_DIM, 0, 0, 0, 1.f);
    } else {
        // -------- fallback (ws too small): round-1 equivalent, 176MB --------
        unsigned short* xb  = (unsigned short*)(ws + 0);
        unsigned short* Pb  = (unsigned short*)(ws + 0); // alias
        unsigned short* Wqb = (unsigned short*)(ws + 32 * MB);
        unsigned short* Wkb = (unsigned short*)(ws + 34 * MB);
        unsigned short* Wvb = (unsigned short*)(ws + 36 * MB);
        unsigned short* Wob = (unsigned short*)(ws + 38 * MB);
        unsigned short* qb  = (unsigned short*)(ws + 40 * MB);
        unsigned short* kb  = (unsigned short*)(ws + 72 * MB);
        unsigned short* vb  = (unsigned short*)(ws + 104 * MB);
        unsigned short* vtb = (unsigned short*)(ws + 136 * MB);
        unsigned short* ctx = (unsigned short*)(ws + 168 * MB);

        cast_f32_bf16<<<nX / 2048, 256, 0, stream>>>(x, xb, nX);
        cast_f32_bf16<<<nW / 2048, 256, 0, stream>>>(Wq, Wqb, nW);
        cast_f32_bf16<<<nW / 2048, 256, 0, stream>>>(Wk, Wkb, nW);
        cast_f32_bf16<<<nW / 2048, 256, 0, stream>>>(Wv, Wvb, nW);
        cast_f32_bf16<<<nW / 2048, 256, 0, stream>>>(Wo, Wob, nW);

        dim3 gproj(D_DIM / 128, SR / 128, 1);
        gemm_bt<unsigned short><<<gproj, 256, 0, stream>>>(xb, Wqb, qb, bq,
            SR, D_DIM, D_DIM, D_DIM, D_DIM, D_DIM, 0, 0, 0, 1.f);
        gemm_bt<unsigned short><<<gproj, 256, 0, stream>>>(xb, Wkb, kb, bk,
            SR, D_DIM, D_DIM, D_DIM, D_DIM, D_DIM, 0, 0, 0, 1.f);
        gemm_bt<unsigned short><<<gproj, 256, 0, stream>>>(xb, Wvb, vb, bv,
            SR, D_DIM, D_DIM, D_DIM, D_DIM, D_DIM, 0, 0, 0, 1.f);

        transpose_sd<<<dim3(D_DIM / 32, S_LEN / 32, BATCH), dim3(32, 8), 0, stream>>>(
            vb, D_DIM, (size_t)S_LEN * D_DIM, vtb, (size_t)D_DIM * S_LEN);

        for (int b = 0; b < BATCH; ++b) {
            const size_t sd = (size_t)b * S_LEN * D_DIM;
            const size_t ds = (size_t)b * D_DIM * S_LEN;
            gemm_bt<unsigned short><<<dim3(S_LEN / 128, S_LEN / 128, 1), 256, 0, stream>>>(
                qb + sd, kb + sd, Pb, nullptr, S_LEN, S_LEN, D_DIM,
                D_DIM, D_DIM, S_LEN, 0, 0, 0, ATTN_SCALE);
            softmax_rows<<<S_LEN, 256, 0, stream>>>(Pb);
            gemm_bt<unsigned short><<<dim3(D_DIM / 128, S_LEN / 128, 1), 256, 0, stream>>>(
                Pb, vtb + ds, ctx, nullptr, S_LEN, D_DIM, S_LEN,
                S_LEN, S_LEN, D_DIM, 0, 0, 0, 1.f);
            gemm_bt<float><<<dim3(D_DIM / 128, S_LEN / 128, 1), 256, 0, stream>>>(
                ctx, Wob, out + sd, bo, S_LEN, D_DIM, D_DIM,
                D_DIM, D_DIM, D_DIM, 0, 0, 0, 1.f);
        }
    }
}